// Round 3
// baseline (4364.748 us; speedup 1.0000x reference)
//
#include <hip/hip_runtime.h>

// ConvLstm (B=64, S=256, H=1024, fp32 in/out) — fused persistent design, PLAIN launch.
// Round 3: bf16 -> fp16 operands (2^-11 vs 2^-9 half-ulp => ~4x less matmul
// quantization noise; round-2 measured absmax 0.043 with bf16, predict ~0.011).
//
//  k_init:      zero per-cluster barrier counters + convert h0 -> fp16 hbuf parity 0.
//  lstm_fused:  256 WGs x 256 threads, 1 block/CU (grid == CU count -> co-resident).
//    - 4 independent clusters of 64 WGs; cluster c owns batches [16c,16c+16).
//    - WG slot j owns hidden channels [16j,16j+16) for ALL 4 gates (i,f,c,o).
//    - Wave w owns K-range [256w,256w+256): split-K over the 4 waves.
//    - Wh and Wx live in VGPRs as pre-packed fp16 MFMA B-fragments (256 VGPRs).
//    - Per step & wave: 32 h-side MFMAs on the critical path; the 32 x-side MFMAs
//      for step t+1 run AFTER the release signal (hidden behind the barrier wait).
//    - h exchanged via fp16 ping-pong buffer in ws; one per-cluster 64-arrival
//      atomic barrier per step (agent-scope release/acquire for cross-XCD vis).
//
// ws layout: [0,1024) barrier counters (cluster c at uint index c*32),
//            [1024, 1024+262144) fp16 h ping-pong buffer [2][64][1024].

#define S_LEN 256
#define H_DIM 1024
#define B_DIM 64

typedef _Float16 v8h __attribute__((ext_vector_type(8)));
typedef float v4f __attribute__((ext_vector_type(4)));

__device__ __forceinline__ v8h pack8h(float4 a, float4 b) {
  v8h r;
  r[0] = (_Float16)a.x; r[1] = (_Float16)a.y; r[2] = (_Float16)a.z; r[3] = (_Float16)a.w;
  r[4] = (_Float16)b.x; r[5] = (_Float16)b.y; r[6] = (_Float16)b.z; r[7] = (_Float16)b.w;
  return r;
}

__device__ __forceinline__ float fsigmoid(float x) { return 1.0f / (1.0f + __expf(-x)); }
__device__ __forceinline__ float ftanh(float x) {
  float e = __expf(2.0f * x);          // +inf for large x is fine: 2/(inf+1)=0
  return 1.0f - 2.0f / (e + 1.0f);
}

__global__ void k_init(const float* __restrict__ h0,
                       _Float16* __restrict__ hbuf,
                       unsigned* __restrict__ bars) {
  int i = blockIdx.x * 256 + threadIdx.x;
  if (i < 256) bars[i] = 0u;
  for (int idx = i; idx < B_DIM * H_DIM; idx += gridDim.x * 256)
    hbuf[idx] = (_Float16)h0[idx];
}

__global__ __launch_bounds__(256, 1) void lstm_fused(
    const float* __restrict__ x, const float* __restrict__ Wx,
    const float* __restrict__ Wh, const float* __restrict__ c0,
    const float* __restrict__ bx, const float* __restrict__ bh,
    const float* __restrict__ bgate, const float* __restrict__ peep,
    _Float16* __restrict__ hbuf, float* __restrict__ out,
    unsigned* __restrict__ bars) {
  __shared__ float pre[4][4][16][17];          // [wave][gate][batch][chan+pad] 17.4 KB
  __shared__ _Float16 ldsx[16 * 1032];         // [batch][k] fp16, padded rows, 33 KB

  const int tid = threadIdx.x;
  const int wid = tid >> 6;                    // wave id = K-range owner
  const int lane = tid & 63;
  const int la = lane & 15;                    // MFMA: A-row (batch) / B-col (chan)
  const int lq = lane >> 4;
  const int cluster = blockIdx.x >> 6;         // 4 clusters x 64 WGs
  const int slot = blockIdx.x & 63;
  const int ch0 = slot * 16;                   // this WG's channel slice
  const int b0 = cluster * 16;                 // this cluster's batch slice

  // ---- one-time: weight fragments into VGPRs (fp16 B-operand layout:
  // lane holds B[k = lq*8 + j][n = la]; MFMA kk covers k in [kk*32, kk*32+32)) ----
  v8h wh_f[4][8], wx_f[4][8];
  {
    const int col = wid * 256 + lq * 8;
#pragma unroll
    for (int g = 0; g < 4; ++g) {
#pragma unroll
      for (int kk = 0; kk < 8; ++kk) {
        const float* ph = Wh + (size_t)(g * 1024 + ch0 + la) * 1024 + col + kk * 32;
        wh_f[g][kk] = pack8h(*(const float4*)ph, *(const float4*)(ph + 4));
        const float* px = Wx + (size_t)(g * 1024 + ch0 + la) * 1024 + col + kk * 32;
        wx_f[g][kk] = pack8h(*(const float4*)px, *(const float4*)(px + 4));
      }
    }
  }

  // ---- elementwise-thread constants (thread <-> (batch bl, chan nn)) ----
  const int bl = tid >> 4;
  const int nn = tid & 15;
  const int gb = b0 + bl;                      // global batch
  const int ch = ch0 + nn;                     // global channel
  float bias_c[4];
#pragma unroll
  for (int g = 0; g < 4; ++g)
    bias_c[g] = bx[g * 1024 + ch] + bh[g * 1024 + ch] + bgate[g * 1024 + ch];
  const float pI = peep[ch], pF = peep[1024 + ch], pO = peep[2048 + ch];
  float c_st = c0[gb * 1024 + ch];             // cell state lives in a register

  auto stage = [&](int ts) {                   // x[:, ts, :] (cluster batches) -> LDS fp16
#pragma unroll
    for (int j = 0; j < 8; ++j) {
      int cid = tid + j * 256;                 // 2048 chunks of 8 floats
      int row = cid >> 7, c8 = cid & 127;
      const float* px = x + (size_t)(b0 + row) * (S_LEN * H_DIM) + (size_t)ts * H_DIM + c8 * 8;
      *(v8h*)(&ldsx[row * 1032 + c8 * 8]) = pack8h(*(const float4*)px, *(const float4*)(px + 4));
    }
  };
  const v4f vzero = {0.f, 0.f, 0.f, 0.f};
  v4f acc[4];
  auto xmfma = [&]() {                         // 32 x-side MFMAs from ldsx
#pragma unroll
    for (int kk = 0; kk < 8; ++kk) {
      v8h ax = *(const v8h*)(&ldsx[la * 1032 + wid * 256 + kk * 32 + lq * 8]);
#pragma unroll
      for (int g = 0; g < 4; ++g)
        acc[g] = __builtin_amdgcn_mfma_f32_16x16x32_f16(ax, wx_f[g][kk], acc[g], 0, 0, 0);
    }
  };

  // ---- prologue: x-partials for step 0, then stage x[1] ----
  stage(0);
  __syncthreads();
#pragma unroll
  for (int g = 0; g < 4; ++g) acc[g] = vzero;
  xmfma();
  __syncthreads();                             // everyone done reading x[0]
  stage(1);                                    // read next iter (synced by loop barriers)

  unsigned* bar = bars + cluster * 32;         // 128B-spaced per-cluster counter

  for (int t = 0; t < S_LEN; ++t) {
    // acc holds x-side partials for step t
    if (t > 0) {
      if (tid == 0) {
        const unsigned tgt = 64u * (unsigned)t;
        while (__hip_atomic_load(bar, __ATOMIC_ACQUIRE, __HIP_MEMORY_SCOPE_AGENT) < tgt)
          __builtin_amdgcn_s_sleep(2);
      }
      __syncthreads();
    }

    // h_{t-1} A-fragments from fp16 ping-pong buffer (parity t&1)
    const _Float16* hb = hbuf + (t & 1) * (B_DIM * H_DIM) +
                         (size_t)(b0 + la) * H_DIM + wid * 256 + lq * 8;
    v8h ah[8];
#pragma unroll
    for (int kk = 0; kk < 8; ++kk) ah[kk] = *(const v8h*)(hb + kk * 32);
#pragma unroll
    for (int kk = 0; kk < 8; ++kk) {
#pragma unroll
      for (int g = 0; g < 4; ++g)
        acc[g] = __builtin_amdgcn_mfma_f32_16x16x32_f16(ah[kk], wh_f[g][kk], acc[g], 0, 0, 0);
    }

    // publish wave partials: D layout col=lane&15, row=(lane>>4)*4+reg
#pragma unroll
    for (int g = 0; g < 4; ++g)
#pragma unroll
      for (int r = 0; r < 4; ++r)
        pre[wid][g][lq * 4 + r][la] = acc[g][r];
    __syncthreads();

    // elementwise gates (thread = one (batch, channel))
    float s[4];
#pragma unroll
    for (int g = 0; g < 4; ++g)
      s[g] = pre[0][g][bl][nn] + pre[1][g][bl][nn] + pre[2][g][bl][nn] +
             pre[3][g][bl][nn] + bias_c[g];
    float ig = fsigmoid(s[0] + pI * c_st);
    float fg = fsigmoid(s[1] + pF * c_st);
    float cn = fg * c_st + ig + ftanh(s[2]);   // NOTE: +ig (reference quirk), not ig*tanh
    float og = fsigmoid(s[3] + pO * cn);
    float hn = og * ftanh(cn);
    c_st = cn;
    out[((size_t)gb * S_LEN + t) * H_DIM + ch] = hn;
    hbuf[((t + 1) & 1) * (B_DIM * H_DIM) + gb * H_DIM + ch] = (_Float16)hn;

    __syncthreads();                           // drains vmcnt: all WG stores in L2

    if (t < S_LEN - 1) {
      if (tid == 0) {
        __threadfence();                       // agent-scope writeback of plain h stores
        __hip_atomic_fetch_add(bar, 1u, __ATOMIC_RELEASE, __HIP_MEMORY_SCOPE_AGENT);
      }
      // off the critical path: x-partials for step t+1, then stage x[t+2]
#pragma unroll
      for (int g = 0; g < 4; ++g) acc[g] = vzero;
      xmfma();                                 // reads ldsx == x[t+1]
      __syncthreads();                         // everyone done reading x[t+1]
      int tn = t + 2 < S_LEN ? t + 2 : S_LEN - 1;
      stage(tn);                               // next read is after next loop-top barrier
    }
  }
}

extern "C" void kernel_launch(void* const* d_in, const int* in_sizes, int n_in,
                              void* d_out, int out_size, void* d_ws, size_t ws_size,
                              hipStream_t stream) {
  (void)in_sizes; (void)n_in; (void)out_size; (void)ws_size;
  const float* x    = (const float*)d_in[0];
  const float* h0   = (const float*)d_in[1];
  const float* c0   = (const float*)d_in[2];
  const float* Wx   = (const float*)d_in[3];
  const float* bx   = (const float*)d_in[4];
  const float* Wh   = (const float*)d_in[5];
  const float* bh   = (const float*)d_in[6];
  const float* peep = (const float*)d_in[7];
  const float* bg   = (const float*)d_in[8];
  float* out = (float*)d_out;

  unsigned* bars = (unsigned*)d_ws;
  _Float16* hbuf = (_Float16*)((char*)d_ws + 1024);

  k_init<<<64, 256, 0, stream>>>(h0, hbuf, bars);
  lstm_fused<<<256, 256, 0, stream>>>(x, Wx, Wh, c0, bx, bh, bg, peep,
                                      hbuf, out, bars);
}

// Round 6
// 1927.424 us; speedup vs baseline: 2.2645x; 2.2645x over previous
//
#include <hip/hip_runtime.h>

// ConvLstm (B=64, S=256, H=1024, fp32 in/out) — fused persistent kernel, round 6.
//
// Round-3 post-mortem: agent-scope ACQUIRE/RELEASE atomics emit whole-L2
// buffer_inv / buffer_wbl2 on gfx950 (per-XCD L2s are non-coherent); the
// acquire-poll invalidated L2 every ~200 cyc => 17 us/step, all pipes idle.
// Rounds 4-6 remove ALL cache-wide ops; coherence is per-access:
//   - h ping-pong + barrier counter use explicit sc0 sc1 (coherence-point)
//     loads/stores/atomics via inline asm, manual s_waitcnt vmcnt(0),
//   - weights, x, out keep normal cached paths.
// Round-5 crash post-mortem: (a) 8-load asm outputs lacked early-clobber so
// the allocator could overlap them with the address pair => wild VMEM address
// => fault; (b) spin-poll via relaxed atomic load could be served stale from
// the local XCD L2 forever => deadlock. Both fixed here: "=&v" outputs, and
// poll/signal as explicit sc0 sc1 / sc1 asm.
//
// Structure: 256 WGs x 256 threads, 1 WG/CU, co-resident (plain launch).
//   4 clusters x 64 WGs; cluster owns 16 batches; WG slot owns 16 channels x
//   4 gates; wave w owns K in [256w,256w+256). Wh/Wx fp16 fragments in VGPRs.
//   Per step: h-side 32 MFMAs on the critical path; x-side 32 MFMAs for step
//   t+1 + LDS staging of x[t+2] run after the signal (hidden behind the wait).
//   One per-cluster 64-arrival barrier per step.
//
// ws layout: [0,1024) barrier counters (cluster c at uint index c*32),
//            [1024, 1024+262144) fp16 h ping-pong buffer [2][64][1024].

#define S_LEN 256
#define H_DIM 1024
#define B_DIM 64

typedef _Float16 v8h __attribute__((ext_vector_type(8)));
typedef float v4f __attribute__((ext_vector_type(4)));
typedef unsigned v4u __attribute__((ext_vector_type(4)));

__device__ __forceinline__ v8h pack8h(float4 a, float4 b) {
  v8h r;
  r[0] = (_Float16)a.x; r[1] = (_Float16)a.y; r[2] = (_Float16)a.z; r[3] = (_Float16)a.w;
  r[4] = (_Float16)b.x; r[5] = (_Float16)b.y; r[6] = (_Float16)b.z; r[7] = (_Float16)b.w;
  return r;
}

__device__ __forceinline__ float fsigmoid(float x) { return 1.0f / (1.0f + __expf(-x)); }
__device__ __forceinline__ float ftanh(float x) {
  float e = __expf(2.0f * x);          // +inf for large x is fine: 2/(inf+1)=0
  return 1.0f - 2.0f / (e + 1.0f);
}

__global__ void k_init(const float* __restrict__ h0,
                       _Float16* __restrict__ hbuf,
                       unsigned* __restrict__ bars) {
  int i = blockIdx.x * 256 + threadIdx.x;
  if (i < 256) bars[i] = 0u;
  for (int idx = i; idx < B_DIM * H_DIM; idx += gridDim.x * 256)
    hbuf[idx] = (_Float16)h0[idx];
  // dispatch-boundary release flushes L2 -> coherence point, so lstm_fused's
  // sc0/sc1 bypass loads see this data.
}

__global__ __launch_bounds__(256, 1) void lstm_fused(
    const float* __restrict__ x, const float* __restrict__ Wx,
    const float* __restrict__ Wh, const float* __restrict__ c0,
    const float* __restrict__ bx, const float* __restrict__ bh,
    const float* __restrict__ bgate, const float* __restrict__ peep,
    _Float16* __restrict__ hbuf, float* __restrict__ out,
    unsigned* __restrict__ bars) {
  __shared__ float pre[4][4][16][18];          // pad 18: store pattern 2-way (free)
  __shared__ _Float16 ldsx[16 * 1032];         // [batch][k] fp16, padded rows

  const int tid = threadIdx.x;
  const int wid = tid >> 6;                    // wave id = K-range owner
  const int lane = tid & 63;
  const int la = lane & 15;                    // MFMA: A-row (batch) / B-col (chan)
  const int lq = lane >> 4;
  const int cluster = blockIdx.x >> 6;         // 4 clusters x 64 WGs
  const int slot = blockIdx.x & 63;
  const int ch0 = slot * 16;                   // this WG's channel slice
  const int b0 = cluster * 16;                 // this cluster's batch slice

  // ---- one-time: weight fragments into VGPRs (fp16 B-operand layout:
  // lane holds B[k = lq*8 + j][n = la]; MFMA kk covers k in [kk*32, kk*32+32)) ----
  v8h wh_f[4][8], wx_f[4][8];
  {
    const int col = wid * 256 + lq * 8;
#pragma unroll
    for (int g = 0; g < 4; ++g) {
#pragma unroll
      for (int kk = 0; kk < 8; ++kk) {
        const float* ph = Wh + (size_t)(g * 1024 + ch0 + la) * 1024 + col + kk * 32;
        wh_f[g][kk] = pack8h(*(const float4*)ph, *(const float4*)(ph + 4));
        const float* px = Wx + (size_t)(g * 1024 + ch0 + la) * 1024 + col + kk * 32;
        wx_f[g][kk] = pack8h(*(const float4*)px, *(const float4*)(px + 4));
      }
    }
  }

  // ---- elementwise-thread constants (thread <-> (batch bl, chan nn)) ----
  const int bl = tid >> 4;
  const int nn = tid & 15;
  const int gb = b0 + bl;                      // global batch
  const int ch = ch0 + nn;                     // global channel
  float bias_c[4];
#pragma unroll
  for (int g = 0; g < 4; ++g)
    bias_c[g] = bx[g * 1024 + ch] + bh[g * 1024 + ch] + bgate[g * 1024 + ch];
  const float pI = peep[ch], pF = peep[1024 + ch], pO = peep[2048 + ch];
  float c_st = c0[gb * 1024 + ch];             // cell state lives in a register

  auto stage = [&](int ts) {                   // x[:, ts, :] (cluster batches) -> LDS fp16
#pragma unroll
    for (int j = 0; j < 8; ++j) {
      int cid = tid + j * 256;                 // 2048 chunks of 8 floats
      int row = cid >> 7, c8 = cid & 127;
      const float* px = x + (size_t)(b0 + row) * (S_LEN * H_DIM) + (size_t)ts * H_DIM + c8 * 8;
      *(v8h*)(&ldsx[row * 1032 + c8 * 8]) = pack8h(*(const float4*)px, *(const float4*)(px + 4));
    }
  };
  const v4f vzero = {0.f, 0.f, 0.f, 0.f};
  v4f acc[4];
  auto xmfma = [&]() {                         // 32 x-side MFMAs from ldsx
#pragma unroll
    for (int kk = 0; kk < 8; ++kk) {
      v8h ax = *(const v8h*)(&ldsx[la * 1032 + wid * 256 + kk * 32 + lq * 8]);
#pragma unroll
      for (int g = 0; g < 4; ++g)
        acc[g] = __builtin_amdgcn_mfma_f32_16x16x32_f16(ax, wx_f[g][kk], acc[g], 0, 0, 0);
    }
  };

  // ---- prologue: x-partials for step 0, then stage x[1] ----
  stage(0);
  __syncthreads();
#pragma unroll
  for (int g = 0; g < 4; ++g) acc[g] = vzero;
  xmfma();
  __syncthreads();                             // everyone done reading x[0]
  stage(1);

  unsigned* bar = bars + cluster * 32;         // 128B-spaced per-cluster counter

  for (int t = 0; t < S_LEN; ++t) {
    // acc holds x-side partials for step t
    if (t > 0) {
      if (tid == 0) {
        const unsigned tgt = 64u * (unsigned)t;
        // poll at the coherence point (sc0 sc1 bypass) — no cache-wide inv
        for (;;) {
          unsigned v;
          asm volatile(
              "global_load_dword %0, %[p], off sc0 sc1\n\t"
              "s_waitcnt vmcnt(0)"
              : "=v"(v) : [p] "v"(bar) : "memory");
          if (v >= tgt) break;
          __builtin_amdgcn_s_sleep(1);
        }
      }
      __syncthreads();
    }

    // h_{t-1} A-fragments: coherence-point loads (bypass L1/L2), batched wait.
    // "=&v" early-clobber: outputs must NOT overlap the address pair (round-5
    // crash: allocator overlapped them => wild address => fault).
    const _Float16* hb = hbuf + (t & 1) * (B_DIM * H_DIM) +
                         (size_t)(b0 + la) * H_DIM + wid * 256 + lq * 8;
    v4u u0, u1, u2, u3, u4, u5, u6, u7;
    asm volatile(
        "global_load_dwordx4 %0, %[p], off sc0 sc1\n\t"
        "global_load_dwordx4 %1, %[p], off offset:64 sc0 sc1\n\t"
        "global_load_dwordx4 %2, %[p], off offset:128 sc0 sc1\n\t"
        "global_load_dwordx4 %3, %[p], off offset:192 sc0 sc1\n\t"
        "global_load_dwordx4 %4, %[p], off offset:256 sc0 sc1\n\t"
        "global_load_dwordx4 %5, %[p], off offset:320 sc0 sc1\n\t"
        "global_load_dwordx4 %6, %[p], off offset:384 sc0 sc1\n\t"
        "global_load_dwordx4 %7, %[p], off offset:448 sc0 sc1\n\t"
        "s_waitcnt vmcnt(0)"
        : "=&v"(u0), "=&v"(u1), "=&v"(u2), "=&v"(u3),
          "=&v"(u4), "=&v"(u5), "=&v"(u6), "=&v"(u7)
        : [p] "v"(hb)
        : "memory");
    v8h ah[8];
    ah[0] = __builtin_bit_cast(v8h, u0); ah[1] = __builtin_bit_cast(v8h, u1);
    ah[2] = __builtin_bit_cast(v8h, u2); ah[3] = __builtin_bit_cast(v8h, u3);
    ah[4] = __builtin_bit_cast(v8h, u4); ah[5] = __builtin_bit_cast(v8h, u5);
    ah[6] = __builtin_bit_cast(v8h, u6); ah[7] = __builtin_bit_cast(v8h, u7);
#pragma unroll
    for (int kk = 0; kk < 8; ++kk) {
#pragma unroll
      for (int g = 0; g < 4; ++g)
        acc[g] = __builtin_amdgcn_mfma_f32_16x16x32_f16(ah[kk], wh_f[g][kk], acc[g], 0, 0, 0);
    }

    // publish wave partials: D layout col=lane&15, row=(lane>>4)*4+reg
#pragma unroll
    for (int g = 0; g < 4; ++g)
#pragma unroll
      for (int r = 0; r < 4; ++r)
        pre[wid][g][lq * 4 + r][la] = acc[g][r];
    __syncthreads();

    // elementwise gates (thread = one (batch, channel))
    float s[4];
#pragma unroll
    for (int g = 0; g < 4; ++g)
      s[g] = pre[0][g][bl][nn] + pre[1][g][bl][nn] + pre[2][g][bl][nn] +
             pre[3][g][bl][nn] + bias_c[g];
    float ig = fsigmoid(s[0] + pI * c_st);
    float fg = fsigmoid(s[1] + pF * c_st);
    float cn = fg * c_st + ig + ftanh(s[2]);   // NOTE: +ig (reference quirk), not ig*tanh
    float og = fsigmoid(s[3] + pO * cn);
    float hn = og * ftanh(cn);
    c_st = cn;

    // h first (its ack gates the barrier), coherence-point write-through;
    // manual vmcnt(0) because asm ops are outside compiler bookkeeping.
    {
      _Float16* hp = hbuf + ((t + 1) & 1) * (B_DIM * H_DIM) + gb * H_DIM + ch;
      unsigned hv = (unsigned)__builtin_bit_cast(unsigned short, (_Float16)hn);
      asm volatile(
          "global_store_short %[p], %[d], off sc0 sc1\n\t"
          "s_waitcnt vmcnt(0)"
          :: [p] "v"(hp), [d] "v"(hv)
          : "memory");
    }
    out[((size_t)gb * S_LEN + t) * H_DIM + ch] = hn;

    __syncthreads();                           // all lanes' h stores acked

    if (t < S_LEN - 1) {
      if (tid == 0) {
        unsigned one = 1u;
        // device-scope atomic at the coherence point; no whole-L2 writeback
        asm volatile(
            "global_atomic_add %[p], %[d], off sc1"
            :: [p] "v"(bar), [d] "v"(one)
            : "memory");
      }
      // off the critical path: x-partials for step t+1, then stage x[t+2]
#pragma unroll
      for (int g = 0; g < 4; ++g) acc[g] = vzero;
      xmfma();                                 // reads ldsx == x[t+1]
      __syncthreads();                         // everyone done reading x[t+1]
      int tn = t + 2 < S_LEN ? t + 2 : S_LEN - 1;
      stage(tn);                               // next read is after next loop-top barrier
    }
  }
}

extern "C" void kernel_launch(void* const* d_in, const int* in_sizes, int n_in,
                              void* d_out, int out_size, void* d_ws, size_t ws_size,
                              hipStream_t stream) {
  (void)in_sizes; (void)n_in; (void)out_size; (void)ws_size;
  const float* x    = (const float*)d_in[0];
  const float* h0   = (const float*)d_in[1];
  const float* c0   = (const float*)d_in[2];
  const float* Wx   = (const float*)d_in[3];
  const float* bx   = (const float*)d_in[4];
  const float* Wh   = (const float*)d_in[5];
  const float* bh   = (const float*)d_in[6];
  const float* peep = (const float*)d_in[7];
  const float* bg   = (const float*)d_in[8];
  float* out = (float*)d_out;

  unsigned* bars = (unsigned*)d_ws;
  _Float16* hbuf = (_Float16*)((char*)d_ws + 1024);

  k_init<<<64, 256, 0, stream>>>(h0, hbuf, bars);
  lstm_fused<<<256, 256, 0, stream>>>(x, Wx, Wh, c0, bx, bh, bg, peep,
                                      hbuf, out, bars);
}